// Round 5
// baseline (166.193 us; speedup 1.0000x reference)
//
#include <hip/hip_runtime.h>

// DissipationNetwork: per-row tiny ICNN, N=2^21 rows, D=2, H=4. VALU/trans-bound map.
//  1) prep_kernel: 35 blocks, one weight-segment each — folds PositiveLinear
//     reparam + log2-domain softplus constants into 267-float wb in d_ws.
//  2) dissip_main: 4 rows/thread = 2 independent float2-packed chains (NP=2),
//     interleaved for trans-pipe ILP. v_pk_fma_f32 for all linear algebra;
//     softplus in log2 domain (raw v_exp_f32/v_log_f32, modifiers folded).
//
// log2-domain: activation a = ln2 * a_hat, a_hat = sp2(z_hat), z_hat = z*log2e.
// sp2(y) = max(y,0) + log2(1 + 2^-|y|). Scale factors telescope; absorbed into
// precomputed weights (input-side *log2e, product-path *ln2, output *ln2 once).

typedef float v2f __attribute__((ext_vector_type(2)));

#define NP 2                 // independent row-pairs per thread (4 rows total)
#define L2Ef 1.4426950408889634f
#define LN2f 0.6931471805599453f

__device__ __forceinline__ v2f vsplat(float s) { v2f r; r.x = s; r.y = s; return r; }
__device__ __forceinline__ v2f vfma(float w, v2f x, v2f a) {
    return __builtin_elementwise_fma(vsplat(w), x, a);   // -> v_pk_fma_f32
}
__device__ __forceinline__ v2f sp2v(v2f y) {
    v2f e, l;
    e.x = __builtin_amdgcn_exp2f(-fabsf(y.x));   // 2^-|y|
    e.y = __builtin_amdgcn_exp2f(-fabsf(y.y));
    l.x = __builtin_amdgcn_logf(1.0f + e.x);     // log2(1+e)
    l.y = __builtin_amdgcn_logf(1.0f + e.y);
    return __builtin_elementwise_max(y, vsplat(0.0f)) + l;
}
__device__ __forceinline__ float posw(float w) {
    // PositiveLinear reparam, EPS=1
    return (w >= 0.0f) ? (w + 0.36787944117144233f) : __expf(w - 1.0f);
}

// ---- transformed weight buffer layout (267 floats) ----
// stage1: [0]w_xl1*L2E(8) [8]b_xl1*L2E(4) [12]w_clin*L2E(8) [20]w_clinm(4)
//         [24]b_clinm(2) [26]w_xin*L2E(8) [34]b_xin*L2E(4)
// stage block (base B=38 / B=132, 94 floats):
//   B+0 w_cpm(16) B+16 b_cpm*L2E(4) B+20 w_clm*LN2(8) B+28 b_clm(2)
//   B+30 w_xl(16) B+46 b_xl*L2E(4)  B+50 LN2*posw(w_cp)(16) B+66 w_cl*L2E(8)
//   B+74 w_xp(16) B+90 b_xp*L2E(4)
// out: [226]w_cpom(16) [242]b_cpom*L2E(4) [246]w_clom*LN2(8) [254]b_clom(2)
//      [256]w_xlo(4) [260]b_xlo*L2E(1) [261]LN2*posw(w_cpo)(4) [265]w_clo*L2E(2)

__global__ __launch_bounds__(64)
void prep_kernel(
    const float* __restrict__ w_xin,  const float* __restrict__ b_xin,
    const float* __restrict__ w_xp1,  const float* __restrict__ b_xp1,
    const float* __restrict__ w_xp2,  const float* __restrict__ b_xp2,
    const float* __restrict__ w_xl1,  const float* __restrict__ b_xl1,
    const float* __restrict__ w_xl2,  const float* __restrict__ b_xl2,
    const float* __restrict__ w_xl3,  const float* __restrict__ b_xl3,
    const float* __restrict__ w_xlo,  const float* __restrict__ b_xlo,
    const float* __restrict__ w_cp1,  const float* __restrict__ w_cp2,
    const float* __restrict__ w_cpo,
    const float* __restrict__ w_cp1m, const float* __restrict__ b_cp1m,
    const float* __restrict__ w_cp2m, const float* __restrict__ b_cp2m,
    const float* __restrict__ w_cpom, const float* __restrict__ b_cpom,
    const float* __restrict__ w_clin, const float* __restrict__ w_cl1,
    const float* __restrict__ w_cl2,  const float* __restrict__ w_clo,
    const float* __restrict__ w_clinm,const float* __restrict__ b_clinm,
    const float* __restrict__ w_cl1m, const float* __restrict__ b_cl1m,
    const float* __restrict__ w_cl2m, const float* __restrict__ b_cl2m,
    const float* __restrict__ w_clom, const float* __restrict__ b_clom,
    float* __restrict__ wb)
{
    const int t = threadIdx.x;
#define SEG(i, dst, src, cnt, EXPR) \
    case i: if (t < (cnt)) { float s_ = (src)[t]; wb[(dst)+t] = (EXPR); } break;
    switch (blockIdx.x) {
    SEG(0,  0,   w_xl1,  8,  L2Ef*s_)
    SEG(1,  8,   b_xl1,  4,  L2Ef*s_)
    SEG(2,  12,  w_clin, 8,  L2Ef*s_)
    SEG(3,  20,  w_clinm,4,  s_)
    SEG(4,  24,  b_clinm,2,  s_)
    SEG(5,  26,  w_xin,  8,  L2Ef*s_)
    SEG(6,  34,  b_xin,  4,  L2Ef*s_)
    SEG(7,  38,  w_cp1m, 16, s_)
    SEG(8,  54,  b_cp1m, 4,  L2Ef*s_)
    SEG(9,  58,  w_cl1m, 8,  LN2f*s_)
    SEG(10, 66,  b_cl1m, 2,  s_)
    SEG(11, 68,  w_xl2,  16, s_)
    SEG(12, 84,  b_xl2,  4,  L2Ef*s_)
    SEG(13, 88,  w_cp1,  16, LN2f*posw(s_))
    SEG(14, 104, w_cl1,  8,  L2Ef*s_)
    SEG(15, 112, w_xp1,  16, s_)
    SEG(16, 128, b_xp1,  4,  L2Ef*s_)
    SEG(17, 132, w_cp2m, 16, s_)
    SEG(18, 148, b_cp2m, 4,  L2Ef*s_)
    SEG(19, 152, w_cl2m, 8,  LN2f*s_)
    SEG(20, 160, b_cl2m, 2,  s_)
    SEG(21, 162, w_xl3,  16, s_)
    SEG(22, 178, b_xl3,  4,  L2Ef*s_)
    SEG(23, 182, w_cp2,  16, LN2f*posw(s_))
    SEG(24, 198, w_cl2,  8,  L2Ef*s_)
    SEG(25, 206, w_xp2,  16, s_)
    SEG(26, 222, b_xp2,  4,  L2Ef*s_)
    SEG(27, 226, w_cpom, 16, s_)
    SEG(28, 242, b_cpom, 4,  L2Ef*s_)
    SEG(29, 246, w_clom, 8,  LN2f*s_)
    SEG(30, 254, b_clom, 2,  s_)
    SEG(31, 256, w_xlo,  4,  s_)
    SEG(32, 260, b_xlo,  1,  L2Ef*s_)
    SEG(33, 261, w_cpo,  4,  LN2f*posw(s_))
    SEG(34, 265, w_clo,  2,  L2Ef*s_)
    }
#undef SEG
}

__device__ __forceinline__ void mid_stage(const float* __restrict__ wb,
                                          v2f xs[NP][4], v2f xh[NP][4],
                                          const v2f XS0[NP][2])
{
    // v[h] = xs[h] * sp2(w_cpm@xh + b_cpm)   — pairs interleaved for trans ILP
    v2f v[NP][4];
    #pragma unroll
    for (int h = 0; h < 4; ++h) {
        float w0 = wb[h*4+0], w1 = wb[h*4+1], w2 = wb[h*4+2], w3 = wb[h*4+3];
        float b  = wb[16+h];
        #pragma unroll
        for (int p = 0; p < NP; ++p) {
            v2f t = vfma(w0, xh[p][0], vfma(w1, xh[p][1],
                    vfma(w2, xh[p][2], vfma(w3, xh[p][3], vsplat(b)))));
            v[p][h] = xs[p][h] * sp2v(t);
        }
    }
    // u[d] = x0s[d] * (w_clm@xh + b_clm)
    v2f u[NP][2];
    #pragma unroll
    for (int d = 0; d < 2; ++d) {
        float w0 = wb[20+d*4+0], w1 = wb[20+d*4+1], w2 = wb[20+d*4+2], w3 = wb[20+d*4+3];
        float b  = wb[28+d];
        #pragma unroll
        for (int p = 0; p < NP; ++p) {
            v2f t = vfma(w0, xh[p][0], vfma(w1, xh[p][1],
                    vfma(w2, xh[p][2], vfma(w3, xh[p][3], vsplat(b)))));
            u[p][d] = XS0[p][d] * t;
        }
    }
    // xs' = sp2(w_xl@xh + b_xl + P@v + w_cl@u);  xh' = sp2(w_xp@xh + b_xp)
    v2f ns[NP][4], nh[NP][4];
    #pragma unroll
    for (int h = 0; h < 4; ++h) {
        float a0 = wb[30+h*4+0], a1 = wb[30+h*4+1], a2 = wb[30+h*4+2], a3 = wb[30+h*4+3];
        float ab = wb[46+h];
        float p0 = wb[50+h*4+0], p1 = wb[50+h*4+1], p2 = wb[50+h*4+2], p3 = wb[50+h*4+3];
        float c0 = wb[66+h*2+0], c1 = wb[66+h*2+1];
        #pragma unroll
        for (int p = 0; p < NP; ++p) {
            v2f t = vfma(a0, xh[p][0], vfma(a1, xh[p][1],
                    vfma(a2, xh[p][2], vfma(a3, xh[p][3], vsplat(ab)))));
            t = vfma(p0, v[p][0], vfma(p1, v[p][1],
                vfma(p2, v[p][2], vfma(p3, v[p][3], t))));
            t = vfma(c0, u[p][0], vfma(c1, u[p][1], t));
            ns[p][h] = sp2v(t);
        }
    }
    #pragma unroll
    for (int h = 0; h < 4; ++h) {
        float w0 = wb[74+h*4+0], w1 = wb[74+h*4+1], w2 = wb[74+h*4+2], w3 = wb[74+h*4+3];
        float b  = wb[90+h];
        #pragma unroll
        for (int p = 0; p < NP; ++p) {
            v2f t = vfma(w0, xh[p][0], vfma(w1, xh[p][1],
                    vfma(w2, xh[p][2], vfma(w3, xh[p][3], vsplat(b)))));
            nh[p][h] = sp2v(t);
        }
    }
    #pragma unroll
    for (int p = 0; p < NP; ++p)
        #pragma unroll
        for (int h = 0; h < 4; ++h) { xs[p][h] = ns[p][h]; xh[p][h] = nh[p][h]; }
}

__global__ __launch_bounds__(256, 3)
void dissip_main(const float* __restrict__ x, const float* __restrict__ xst,
                 const float* __restrict__ wb, float* __restrict__ out, int n)
{
    const int tid = blockIdx.x * blockDim.x + threadIdx.x;
    const int r0  = tid * (2 * NP);          // 4 rows per thread
    if (r0 >= n) return;
    const bool full = (r0 + 2 * NP <= n);

    // pair p, v2f element e = row r0 + 2p + e
    v2f X0[NP][2], XS0[NP][2];
    if (full) {
        const float4 xa = *(const float4*)(x   + (size_t)r0 * 2);
        const float4 xb = *(const float4*)(x   + (size_t)r0 * 2 + 4);
        const float4 sa = *(const float4*)(xst + (size_t)r0 * 2);
        const float4 sb = *(const float4*)(xst + (size_t)r0 * 2 + 4);
        X0[0][0].x = xa.x;  X0[0][0].y = xa.z;  X0[0][1].x = xa.y;  X0[0][1].y = xa.w;
        X0[1][0].x = xb.x;  X0[1][0].y = xb.z;  X0[1][1].x = xb.y;  X0[1][1].y = xb.w;
        XS0[0][0].x = sa.x; XS0[0][0].y = sa.z; XS0[0][1].x = sa.y; XS0[0][1].y = sa.w;
        XS0[1][0].x = sb.x; XS0[1][0].y = sb.z; XS0[1][1].x = sb.y; XS0[1][1].y = sb.w;
    } else {
        #pragma unroll
        for (int p = 0; p < NP; ++p) {
            X0[p][0] = vsplat(0.0f); X0[p][1] = vsplat(0.0f);
            XS0[p][0] = vsplat(0.0f); XS0[p][1] = vsplat(0.0f);
            #pragma unroll
            for (int e = 0; e < 2; ++e) {
                int row = r0 + 2*p + e;
                if (row < n) {
                    if (e == 0) {
                        X0[p][0].x  = x[(size_t)row*2];   X0[p][1].x  = x[(size_t)row*2+1];
                        XS0[p][0].x = xst[(size_t)row*2]; XS0[p][1].x = xst[(size_t)row*2+1];
                    } else {
                        X0[p][0].y  = x[(size_t)row*2];   X0[p][1].y  = x[(size_t)row*2+1];
                        XS0[p][0].y = xst[(size_t)row*2]; XS0[p][1].y = xst[(size_t)row*2+1];
                    }
                }
            }
        }
    }

    v2f xs[NP][4], xh[NP][4];

    // ---- stage 1 ----
    v2f tcl[NP][2];
    {
        float m00=wb[20], m01=wb[21], m10=wb[22], m11=wb[23], c0=wb[24], c1=wb[25];
        #pragma unroll
        for (int p = 0; p < NP; ++p) {
            tcl[p][0] = XS0[p][0] * vfma(m00, X0[p][0], vfma(m01, X0[p][1], vsplat(c0)));
            tcl[p][1] = XS0[p][1] * vfma(m10, X0[p][0], vfma(m11, X0[p][1], vsplat(c1)));
        }
    }
    #pragma unroll
    for (int h = 0; h < 4; ++h) {
        float a0 = wb[h*2+0], a1 = wb[h*2+1], ab = wb[8+h];
        float c0 = wb[12+h*2+0], c1 = wb[12+h*2+1];
        #pragma unroll
        for (int p = 0; p < NP; ++p) {
            v2f a = vfma(a0, X0[p][0], vfma(a1, X0[p][1], vsplat(ab)));
            a = vfma(c0, tcl[p][0], vfma(c1, tcl[p][1], a));
            xs[p][h] = sp2v(a);
        }
    }
    #pragma unroll
    for (int h = 0; h < 4; ++h) {
        float w0 = wb[26+h*2+0], w1 = wb[26+h*2+1], b = wb[34+h];
        #pragma unroll
        for (int p = 0; p < NP; ++p)
            xh[p][h] = sp2v(vfma(w0, X0[p][0], vfma(w1, X0[p][1], vsplat(b))));
    }

    // ---- stages 2, 3 ----
    mid_stage(wb + 38,  xs, xh, XS0);
    mid_stage(wb + 132, xs, xh, XS0);

    // ---- output stage ----
    const float* ob = wb + 226;
    v2f o[NP];
    {
        v2f vv[NP][4];
        #pragma unroll
        for (int h = 0; h < 4; ++h) {
            float w0 = ob[h*4+0], w1 = ob[h*4+1], w2 = ob[h*4+2], w3 = ob[h*4+3];
            float b  = ob[16+h];
            #pragma unroll
            for (int p = 0; p < NP; ++p) {
                v2f t = vfma(w0, xh[p][0], vfma(w1, xh[p][1],
                        vfma(w2, xh[p][2], vfma(w3, xh[p][3], vsplat(b)))));
                vv[p][h] = xs[p][h] * sp2v(t);
            }
        }
        v2f uu[NP][2];
        #pragma unroll
        for (int d = 0; d < 2; ++d) {
            float w0 = ob[20+d*4+0], w1 = ob[20+d*4+1], w2 = ob[20+d*4+2], w3 = ob[20+d*4+3];
            float b  = ob[28+d];
            #pragma unroll
            for (int p = 0; p < NP; ++p) {
                v2f t = vfma(w0, xh[p][0], vfma(w1, xh[p][1],
                        vfma(w2, xh[p][2], vfma(w3, xh[p][3], vsplat(b)))));
                uu[p][d] = XS0[p][d] * t;
            }
        }
        float l0 = ob[30], l1 = ob[31], l2 = ob[32], l3 = ob[33], lb = ob[34];
        float p0 = ob[35], p1 = ob[36], p2 = ob[37], p3 = ob[38];
        float c0 = ob[39], c1 = ob[40];
        #pragma unroll
        for (int p = 0; p < NP; ++p) {
            v2f t = vfma(l0, xh[p][0], vfma(l1, xh[p][1],
                    vfma(l2, xh[p][2], vfma(l3, xh[p][3], vsplat(lb)))));
            t = vfma(p0, vv[p][0], vfma(p1, vv[p][1],
                vfma(p2, vv[p][2], vfma(p3, vv[p][3], t))));
            t = vfma(c0, uu[p][0], vfma(c1, uu[p][1], t));
            o[p] = vsplat(LN2f) * sp2v(t);
        }
    }

    if (full) {
        *(float4*)(out + r0) = make_float4(o[0].x, o[0].y, o[1].x, o[1].y);
    } else {
        #pragma unroll
        for (int p = 0; p < NP; ++p) {
            if (r0 + 2*p     < n) out[r0 + 2*p]     = o[p].x;
            if (r0 + 2*p + 1 < n) out[r0 + 2*p + 1] = o[p].y;
        }
    }
}

extern "C" void kernel_launch(void* const* d_in, const int* in_sizes, int n_in,
                              void* d_out, int out_size, void* d_ws, size_t ws_size,
                              hipStream_t stream) {
    const float* p[37];
    for (int i = 0; i < 37; ++i) p[i] = (const float*)d_in[i];
    float* wb = (float*)d_ws;   // 267 floats
    const int n = in_sizes[0] / 2;  // N rows (D=2)

    prep_kernel<<<dim3(35), dim3(64), 0, stream>>>(
        p[2],  p[3],  p[4],  p[5],  p[6],  p[7],
        p[8],  p[9],  p[10], p[11], p[12], p[13],
        p[14], p[15],
        p[16], p[17], p[18],
        p[19], p[20], p[21], p[22], p[23], p[24],
        p[25], p[26], p[27], p[28],
        p[29], p[30], p[31], p[32], p[33], p[34],
        p[35], p[36],
        wb);

    const int threads = 256;
    const int rows_per_block = threads * 2 * NP;
    const int blocks = (n + rows_per_block - 1) / rows_per_block;
    dissip_main<<<dim3(blocks), dim3(threads), 0, stream>>>(
        p[0], p[1], wb, (float*)d_out, n);
}